// Round 5
// baseline (328.503 us; speedup 1.0000x reference)
//
#include <hip/hip_runtime.h>
#include <hip/hip_bf16.h>

// Problem constants
#define Bn 4
#define Tn 2048
#define Cn 1024
#define Hn 16
#define Dn 64
#define Kdim 1024

typedef __bf16 bf16x8 __attribute__((ext_vector_type(8)));
typedef float f32x4 __attribute__((ext_vector_type(4)));
union B8 { uint4 u; bf16x8 f; ushort s[8]; };

static __device__ __forceinline__ ushort f2bf(float x) {
    __hip_bfloat16 h = __float2bfloat16(x);
    return *(ushort*)&h;
}

#define AS1 __attribute__((address_space(1)))
#define AS3 __attribute__((address_space(3)))

static __device__ __forceinline__ void gload_lds16(const ushort* g, ushort* l) {
    __builtin_amdgcn_global_load_lds((AS1 const uint4*)(const void*)g,
                                     (AS3 uint4*)(void*)l, 16, 0, 0);
}

// ---------------------------------------------------------------------------
// Fused prep: grid.y selects section.
//  y==0 (4096 blocks): X fp32 -> bf16 (layout preserved)
//  y==1 (96x32 via blockIdx.x): qkv_w [K,3C] -> Wqt [3C,K] bf16
//  y==2 (32x32): o_w [K,C] -> Wot [C,K] bf16
// ---------------------------------------------------------------------------
__global__ __launch_bounds__(256) void prep_fused(
    const float* __restrict__ X, const float* __restrict__ qkv_w,
    const float* __restrict__ o_w,
    ushort* __restrict__ Xb, ushort* __restrict__ Wqt, ushort* __restrict__ Wot)
{
    if (blockIdx.y == 0) {
        int i = (blockIdx.x * 256 + threadIdx.x) * 8;
        float4 a = *(const float4*)&X[i];
        float4 b = *(const float4*)&X[i + 4];
        ushort4 o0, o1;
        o0.x = f2bf(a.x); o0.y = f2bf(a.y); o0.z = f2bf(a.z); o0.w = f2bf(a.w);
        o1.x = f2bf(b.x); o1.y = f2bf(b.y); o1.z = f2bf(b.z); o1.w = f2bf(b.w);
        *(ushort4*)&Xb[i] = o0;
        *(ushort4*)&Xb[i + 4] = o1;
        return;
    }
    // transpose sections
    const float* W; ushort* Wt; int N, bx;
    if (blockIdx.y == 1) { W = qkv_w; Wt = Wqt; N = 3 * Cn; bx = blockIdx.x; }
    else                 { W = o_w;   Wt = Wot; N = Cn;     bx = blockIdx.x; }
    if (bx >= (N / 32) * 32) return;
    const int n0 = (bx % (N / 32)) * 32, k0 = (bx / (N / 32)) * 32;
    __shared__ float Ls[32][33];
    const int tx = threadIdx.x & 31, ty = threadIdx.x >> 5;
    #pragma unroll
    for (int i = 0; i < 4; i++) {
        int r = ty + i * 8;
        Ls[r][tx] = W[(size_t)(k0 + r) * N + n0 + tx];
    }
    __syncthreads();
    #pragma unroll
    for (int i = 0; i < 4; i++) {
        int r = ty + i * 8;
        Wt[(size_t)(n0 + r) * Kdim + k0 + tx] = f2bf(Ls[tx][r]);
    }
}

// ---------------------------------------------------------------------------
// bf16 MFMA GEMM (m97 structure): C[M,N] = A[M,K] @ Bt[N,K]^T (+bias).
// EPI 0: fp32 out + bias.
// EPI 1: bf16 Q[B,H,T,D] (pre-scaled by D^-0.5*log2(e)), K[B,H,T,D],
//        V^T[B,H,D,T]. Epilogue round-trips each wave's 64x64 tile through
//        LDS (XOR bank swizzle) -> fully coalesced uint4 global stores.
// ---------------------------------------------------------------------------
template <int EPI>
__global__ __launch_bounds__(256) void gemm_bt(
    const ushort* __restrict__ A, const ushort* __restrict__ Bt,
    const float* __restrict__ bias,
    float* __restrict__ Out, ushort* __restrict__ Qb,
    ushort* __restrict__ Kb, ushort* __restrict__ Vtb)
{
    const int m0 = blockIdx.y * 128;
    const int n0 = blockIdx.x * 128;
    const int t  = threadIdx.x;
    const int wave = t >> 6, lane = t & 63;
    const int ln = lane & 15, quad = lane >> 4;
    const int wm = wave >> 1, wn = wave & 1;

    __shared__ ushort As[128 * 64];
    __shared__ ushort Bs[128 * 64];

    f32x4 acc[4][4] = {};

    for (int k0 = 0; k0 < Kdim; k0 += 64) {
        __syncthreads();
        #pragma unroll
        for (int it = 0; it < 4; it++) {
            int c = it * 256 + wave * 64 + lane;
            int row = c >> 3, seg = c & 7;
            int gseg = seg ^ (row & 7);
            gload_lds16(&A [(size_t)(m0 + row) * Kdim + k0 + gseg * 8], &As[c * 8]);
            gload_lds16(&Bt[(size_t)(n0 + row) * Kdim + k0 + gseg * 8], &Bs[c * 8]);
        }
        __syncthreads();

        #pragma unroll
        for (int ks = 0; ks < 2; ks++) {
            bf16x8 af[4], bf[4];
            #pragma unroll
            for (int mm = 0; mm < 4; mm++) {
                int row = wm * 64 + mm * 16 + ln;
                int seg = (ks * 4 + quad) ^ (ln & 7);
                B8 tmp; tmp.u = *(const uint4*)&As[row * 64 + seg * 8];
                af[mm] = tmp.f;
            }
            #pragma unroll
            for (int nn = 0; nn < 4; nn++) {
                int row = wn * 64 + nn * 16 + ln;
                int seg = (ks * 4 + quad) ^ (ln & 7);
                B8 tmp; tmp.u = *(const uint4*)&Bs[row * 64 + seg * 8];
                bf[nn] = tmp.f;
            }
            #pragma unroll
            for (int mm = 0; mm < 4; mm++)
                #pragma unroll
                for (int nn = 0; nn < 4; nn++)
                    acc[mm][nn] = __builtin_amdgcn_mfma_f32_16x16x32_bf16(
                        af[mm], bf[nn], acc[mm][nn], 0, 0, 0);
        }
    }

    if (EPI == 0) {
        #pragma unroll
        for (int nn = 0; nn < 4; nn++) {
            int n = n0 + wn * 64 + nn * 16 + ln;
            float bv = bias[n];
            #pragma unroll
            for (int mm = 0; mm < 4; mm++) {
                int mbase = m0 + wm * 64 + mm * 16 + quad * 4;
                #pragma unroll
                for (int reg = 0; reg < 4; reg++)
                    Out[(size_t)(mbase + reg) * 1024 + n] = acc[mm][nn][reg] + bv;
            }
        }
    } else {
        const int nb = n0 + wn * 64;
        const int which = nb >> 10;            // 0=Q 1=K 2=V
        const int h = (nb & 1023) >> 6;
        const float scale = (which == 0) ? 0.125f * 1.44269504088896f : 1.0f;
        const int b_ = m0 >> 11;               // 128-row tile within one batch
        const int t0 = (m0 & 2047) + wm * 64;

        __syncthreads();   // fragments consumed; reuse As/Bs as transpose pads
        ushort* tile = ((wave & 2) ? Bs : As) + (wave & 1) * 4096;  // 64x64/wave

        if (which == 2) {
            // LDS tile [n=d][m=token] (XOR-swizzled), rows -> [B,H,D,T]
            #pragma unroll
            for (int nn = 0; nn < 4; nn++) {
                float bv = bias[nb + nn * 16 + ln];
                #pragma unroll
                for (int mm = 0; mm < 4; mm++)
                    #pragma unroll
                    for (int reg = 0; reg < 4; reg++) {
                        int m = mm * 16 + quad * 4 + reg;
                        int n = nn * 16 + ln;
                        tile[n * 64 + (m ^ (((n >> 1) & 7) * 8))] =
                            f2bf(acc[mm][nn][reg] + bv);
                    }
            }
            #pragma unroll
            for (int it = 0; it < 8; it++) {
                int idx = it * 64 + lane;
                int row = idx >> 3, seg = idx & 7;   // row = d, seg = token/8
                uint4 v = *(const uint4*)&tile[row * 64 +
                              ((seg * 8) ^ (((row >> 1) & 7) * 8))];
                *(uint4*)&Vtb[((size_t)((b_ * Hn + h) * Dn) + row) * Tn + t0 + seg * 8] = v;
            }
        } else {
            // LDS tile [m=token][n=d] (XOR-swizzled), rows -> [B,H,T,D]
            ushort* dst = (which == 0) ? Qb : Kb;
            #pragma unroll
            for (int nn = 0; nn < 4; nn++) {
                float bv = bias[nb + nn * 16 + ln];
                #pragma unroll
                for (int mm = 0; mm < 4; mm++)
                    #pragma unroll
                    for (int reg = 0; reg < 4; reg++) {
                        int m = mm * 16 + quad * 4 + reg;
                        int n = nn * 16 + ln;
                        tile[m * 64 + (n ^ (((m >> 1) & 7) * 8))] =
                            f2bf((acc[mm][nn][reg] + bv) * scale);
                    }
            }
            #pragma unroll
            for (int it = 0; it < 8; it++) {
                int idx = it * 64 + lane;
                int row = idx >> 3, seg = idx & 7;   // row = token, seg = d/8
                uint4 v = *(const uint4*)&tile[row * 64 +
                              ((seg * 8) ^ (((row >> 1) & 7) * 8))];
                *(uint4*)&dst[((size_t)((b_ * Hn + h) * Tn) + t0 + row) * Dn + seg * 8] = v;
            }
        }
    }
}

// ---------------------------------------------------------------------------
// Balanced tile partition for 12 blocks/bh at cost(j) = (j>>1)+1 chunks:
// 8 pair-blocks of 23 chunks + 4 blocks of 22 (triples/quintuples).
// Covers j=0..31 exactly once; max/min imbalance 23/22 = 4.5%.
// ---------------------------------------------------------------------------
static __device__ const signed char g_tiles[12][5] = {
    {31, 13, -1, -1, -1}, {30, 12, -1, -1, -1},
    {29, 15, -1, -1, -1}, {28, 14, -1, -1, -1},
    {27, 17, -1, -1, -1}, {26, 16, -1, -1, -1},
    {25, 19, -1, -1, -1}, {24, 18, -1, -1, -1},
    {23, 11,  7, -1, -1}, {22, 10,  6, -1, -1},
    {21,  9,  5,  3,  1}, {20,  8,  4,  2,  0}};

// ---------------------------------------------------------------------------
// Flash attention (r17): 64-row q-tiles, 12 blocks per bh via g_tiles
// partition -> grid (64,12) = 768 blocks = exactly 3/CU, all resident,
// <=4.5% imbalance. launch_bounds(256,3) -> ~168 VGPR budget: the r3
// structure (vA/vB 2-deep V pipeline, demand ~140) fits with slack ->
// ZERO spill (r14-r16 all spilled against the 128-cap's 64-arch half).
// vA/vB gks0/1 issued before STAGE_K so their waits never drain the K
// prefetch; gks2/3 refilled right after their buffer's PV MFMAs consume
// it -> full QK-phase of latency cover.
// Softmax: ones-MFMA row-sum, defer-max (THR=8 log2), tree max.
// LDS = Ks 32KB + Ps 4.25KB = 37.1KB; x3 blocks = 112KB <= 160KB.
// ---------------------------------------------------------------------------
__global__ __launch_bounds__(256, 3) void attn_mfma(
    const ushort* __restrict__ Qb, const ushort* __restrict__ Kb,
    const ushort* __restrict__ Vtb, ushort* __restrict__ Ob)
{
    const int bh   = blockIdx.x;       // 0..63 (fastest-varying)
    const int w    = blockIdx.y;       // 0..11: tile-set within bh
    const int t    = threadIdx.x;
    const int wave = t >> 6, lane = t & 63;
    const int ln   = lane & 15, quad = lane >> 4;

    __shared__ ushort Ks[2][128 * 64];  // [key][d], xor-swizzled segs, 2x16KB
    __shared__ ushort Ps[4][16 * 34];   // per-wave P slice [q(16)][key(32)+pad]

    const ushort* KgB = Kb  + (size_t)bh * Tn * Dn;
    const ushort* VgB = Vtb + (size_t)bh * Dn * Tn;
    const int b_ = bh >> 4, h = bh & 15;

    // all-ones bf16 A-fragment for the l row-sum MFMA
    B8 ones;
    #pragma unroll
    for (int jj = 0; jj < 8; jj++) ones.s[jj] = 0x3F80;

    #define STAGE_K(kc, buf)                                                   \
        do {                                                                   \
            _Pragma("unroll")                                                  \
            for (int it = 0; it < 4; it++) {                                   \
                int c = it * 256 + wave * 64 + lane;                           \
                int row = c >> 3, seg = c & 7;                                 \
                int gs = seg ^ (row & 7);                                      \
                gload_lds16(&KgB[(size_t)((kc) * 128 + row) * Dn + gs * 8],    \
                            &Ks[buf][c * 8]);                                  \
            }                                                                  \
        } while (0)

    #define LOADV(dst, gks)                                                    \
        do {                                                                   \
            _Pragma("unroll")                                                  \
            for (int ctd = 0; ctd < 4; ctd++)                                  \
                dst[ctd].u = *(const uint4*)&VgB[                              \
                    (size_t)(ctd * 16 + ln) * Tn + kc * 128 + (gks) * 32 +     \
                    quad * 8];                                                 \
        } while (0)

    for (int ti = 0; ti < 5; ti++) {
        const int j = g_tiles[w][ti];        // 64-row tile index, heavy first
        if (j < 0) break;
        const int nc = (j >> 1) + 1;         // 128-key chunks covering tile
        if (ti) __syncthreads();             // protect Ks reuse across tiles

        int cur = 0;
        STAGE_K(0, 0);

        const int q0 = j * 64;
        const ushort* Qg = Qb + ((size_t)bh * Tn + q0 + wave * 16) * Dn;
        bf16x8 qf[2];
        #pragma unroll
        for (int ks = 0; ks < 2; ks++) {
            B8 tmp; tmp.u = *(const uint4*)&Qg[ln * 64 + ks * 32 + quad * 8];
            qf[ks] = tmp.f;
        }

        f32x4 Oacc[4] = {};   // O^T [d-subtile], lane ln = q
        f32x4 Lacc = {};      // row-sum accumulator (rows replicated)
        float m_r = -1e30f;

        for (int kc = 0; kc < nc; kc++) {
            __syncthreads();   // publishes K(kc); drains prefetch issued last iter

            // V^T pipeline, 2-deep: gks 0/1 issued before STAGE_K so their
            // waits never force the K prefetch to drain.
            B8 vA[4], vB[4];
            LOADV(vA, 0);
            LOADV(vB, 1);

            if (kc + 1 < nc) STAGE_K(kc + 1, cur ^ 1);   // prefetch next chunk

            // S^T = K Q^T: rows = keys (128 = 8 ct), cols = q (16, lane ln)
            const ushort* Kc = Ks[cur];
            f32x4 S[8] = {};
            #pragma unroll
            for (int ks = 0; ks < 2; ks++)
                #pragma unroll
                for (int ct = 0; ct < 8; ct++) {
                    B8 a; a.u = *(const uint4*)&Kc[(ct * 16 + ln) * 64 +
                                                   (((ks * 4 + quad) ^ (ln & 7)) * 8)];
                    S[ct] = __builtin_amdgcn_mfma_f32_16x16x32_bf16(
                        a.f, qf[ks], S[ct], 0, 0, 0);
                }

            if (kc == nc - 1) {   // causal mask on diagonal chunk
                int ql = q0 + wave * 16 + ln;
                #pragma unroll
                for (int ct = 0; ct < 8; ct++) {
                    int keyl = kc * 128 + ct * 16 + quad * 4;
                    #pragma unroll
                    for (int reg = 0; reg < 4; reg++)
                        if (keyl + reg > ql) S[ct][reg] = -1e30f;
                }
            }

            // per-lane chunk max (tree), reduce over quads
            float ctm[8];
            #pragma unroll
            for (int ct = 0; ct < 8; ct++)
                ctm[ct] = fmaxf(fmaxf(S[ct][0], S[ct][1]),
                                fmaxf(S[ct][2], S[ct][3]));
            float pm = fmaxf(fmaxf(fmaxf(ctm[0], ctm[1]), fmaxf(ctm[2], ctm[3])),
                             fmaxf(fmaxf(ctm[4], ctm[5]), fmaxf(ctm[6], ctm[7])));
            pm = fmaxf(pm, __shfl_xor(pm, 16));
            pm = fmaxf(pm, __shfl_xor(pm, 32));

            // defer-max: only rescale when some lane's max grew by > 8 (log2)
            if (__any(pm > m_r + 8.0f)) {
                float mn = fmaxf(m_r, pm);
                float alpha = exp2f(m_r - mn);
                m_r = mn;
                #pragma unroll
                for (int ctd = 0; ctd < 4; ctd++)
                    Oacc[ctd] *= alpha;
                Lacc *= alpha;
            }

            // 4 passes: write 32-key P slice, immediately consume with PV step;
            // l row-sum folded into an extra ones-MFMA per slice.
            // V buffer for pass p is refilled with gks p+2 right after use.
            ushort* Pw = Ps[wave];
            #pragma unroll
            for (int p = 0; p < 4; p++) {
                #pragma unroll
                for (int ct_h = 0; ct_h < 2; ct_h++) {
                    int ct = p * 2 + ct_h;
                    ushort4 o;
                    #pragma unroll
                    for (int reg = 0; reg < 4; reg++) {
                        float pv = exp2f(S[ct][reg] - m_r);
                        ((ushort*)&o)[reg] = f2bf(pv);
                    }
                    *(ushort4*)&Pw[ln * 34 + ct_h * 16 + quad * 4] = o;
                }
                B8 pfr; pfr.u = *(const uint4*)&Pw[ln * 34 + quad * 8];
                #pragma unroll
                for (int ctd = 0; ctd < 4; ctd++)
                    Oacc[ctd] = __builtin_amdgcn_mfma_f32_16x16x32_bf16(
                        ((p & 1) ? vB[ctd].f : vA[ctd].f), pfr.f, Oacc[ctd], 0, 0, 0);
                Lacc = __builtin_amdgcn_mfma_f32_16x16x32_bf16(
                    ones.f, pfr.f, Lacc, 0, 0, 0);
                if (p == 0) LOADV(vA, 2);
                if (p == 1) LOADV(vB, 3);
            }
            cur ^= 1;
        }

        // epilogue: bf16 attn_out [B*T][C]; lane ln = token, regs = d
        {
            float inv = 1.0f / Lacc[0];
            int token = q0 + wave * 16 + ln;
            ushort* dst = Ob + ((size_t)(b_ * Tn + token)) * Cn + h * 64;
            #pragma unroll
            for (int ctd = 0; ctd < 4; ctd++) {
                ushort4 o;
                #pragma unroll
                for (int reg = 0; reg < 4; reg++)
                    ((ushort*)&o)[reg] = f2bf(Oacc[ctd][reg] * inv);
                *(ushort4*)&dst[ctd * 16 + quad * 4] = o;
            }
        }
    }
    #undef STAGE_K
    #undef LOADV
}

// ---------------------------------------------------------------------------
extern "C" void kernel_launch(void* const* d_in, const int* in_sizes, int n_in,
                              void* d_out, int out_size, void* d_ws, size_t ws_size,
                              hipStream_t stream) {
    const float* X     = (const float*)d_in[0];
    const float* qkv_w = (const float*)d_in[1];
    const float* qkv_b = (const float*)d_in[2];
    const float* o_w   = (const float*)d_in[3];
    const float* o_b   = (const float*)d_in[4];
    float* out = (float*)d_out;

    const size_t BTC = (size_t)Bn * Tn * Cn;     // 8388608
    ushort* Xb  = (ushort*)d_ws;                 // bf16 [8192,1024]
    ushort* Wqt = Xb  + BTC;                     // bf16 [3072,1024]
    ushort* Wot = Wqt + 3 * Cn * Cn;             // bf16 [1024,1024]
    ushort* Qb  = Wot + Cn * Cn;                 // bf16 [B,H,T,D]
    ushort* Kb  = Qb  + BTC;
    ushort* Vtb = Kb  + BTC;                     // bf16 [B,H,D,T]
    ushort* Ao  = Vtb + BTC;                     // bf16 [B*T,C]

    // fused prep: y=0 cast (4096 blocks), y=1 qkv_w transpose (96*32=3072),
    // y=2 o_w transpose (32*32=1024). grid.x = max section size.
    prep_fused<<<dim3(4096, 3), 256, 0, stream>>>(X, qkv_w, o_w, Xb, Wqt, Wot);

    gemm_bt<1><<<dim3(3 * Cn / 128, 8192 / 128), 256, 0, stream>>>(
        Xb, Wqt, qkv_b, nullptr, Qb, Kb, Vtb);
    attn_mfma<<<dim3(Bn * Hn, 12), 256, 0, stream>>>(Qb, Kb, Vtb, Ao);
    gemm_bt<0><<<dim3(Cn / 128, 8192 / 128), 256, 0, stream>>>(
        Ao, Wot, o_b, out, nullptr, nullptr, nullptr);
}

// Round 6
// 271.839 us; speedup vs baseline: 1.2084x; 1.2084x over previous
//
#include <hip/hip_runtime.h>
#include <hip/hip_bf16.h>

// Problem constants
#define Bn 4
#define Tn 2048
#define Cn 1024
#define Hn 16
#define Dn 64
#define Kdim 1024

typedef __bf16 bf16x8 __attribute__((ext_vector_type(8)));
typedef float f32x4 __attribute__((ext_vector_type(4)));
union B8 { uint4 u; bf16x8 f; ushort s[8]; };

static __device__ __forceinline__ ushort f2bf(float x) {
    __hip_bfloat16 h = __float2bfloat16(x);
    return *(ushort*)&h;
}

#define AS1 __attribute__((address_space(1)))
#define AS3 __attribute__((address_space(3)))

static __device__ __forceinline__ void gload_lds16(const ushort* g, ushort* l) {
    __builtin_amdgcn_global_load_lds((AS1 const uint4*)(const void*)g,
                                     (AS3 uint4*)(void*)l, 16, 0, 0);
}

// ---------------------------------------------------------------------------
// Fused prep: grid.y selects section.
//  y==0 (4096 blocks): X fp32 -> bf16 (layout preserved)
//  y==1 (96x32 via blockIdx.x): qkv_w [K,3C] -> Wqt [3C,K] bf16
//  y==2 (32x32): o_w [K,C] -> Wot [C,K] bf16
// ---------------------------------------------------------------------------
__global__ __launch_bounds__(256) void prep_fused(
    const float* __restrict__ X, const float* __restrict__ qkv_w,
    const float* __restrict__ o_w,
    ushort* __restrict__ Xb, ushort* __restrict__ Wqt, ushort* __restrict__ Wot)
{
    if (blockIdx.y == 0) {
        int i = (blockIdx.x * 256 + threadIdx.x) * 8;
        float4 a = *(const float4*)&X[i];
        float4 b = *(const float4*)&X[i + 4];
        ushort4 o0, o1;
        o0.x = f2bf(a.x); o0.y = f2bf(a.y); o0.z = f2bf(a.z); o0.w = f2bf(a.w);
        o1.x = f2bf(b.x); o1.y = f2bf(b.y); o1.z = f2bf(b.z); o1.w = f2bf(b.w);
        *(ushort4*)&Xb[i] = o0;
        *(ushort4*)&Xb[i + 4] = o1;
        return;
    }
    // transpose sections
    const float* W; ushort* Wt; int N, bx;
    if (blockIdx.y == 1) { W = qkv_w; Wt = Wqt; N = 3 * Cn; bx = blockIdx.x; }
    else                 { W = o_w;   Wt = Wot; N = Cn;     bx = blockIdx.x; }
    if (bx >= (N / 32) * 32) return;
    const int n0 = (bx % (N / 32)) * 32, k0 = (bx / (N / 32)) * 32;
    __shared__ float Ls[32][33];
    const int tx = threadIdx.x & 31, ty = threadIdx.x >> 5;
    #pragma unroll
    for (int i = 0; i < 4; i++) {
        int r = ty + i * 8;
        Ls[r][tx] = W[(size_t)(k0 + r) * N + n0 + tx];
    }
    __syncthreads();
    #pragma unroll
    for (int i = 0; i < 4; i++) {
        int r = ty + i * 8;
        Wt[(size_t)(n0 + r) * Kdim + k0 + tx] = f2bf(Ls[tx][r]);
    }
}

// ---------------------------------------------------------------------------
// bf16 MFMA GEMM (m97 structure): C[M,N] = A[M,K] @ Bt[N,K]^T (+bias).
// EPI 0: fp32 out + bias.
// EPI 1: bf16 Q[B,H,T,D] (pre-scaled by D^-0.5*log2(e)), K[B,H,T,D],
//        V^T[B,H,D,T]. Epilogue round-trips each wave's 64x64 tile through
//        LDS (XOR bank swizzle) -> fully coalesced uint4 global stores.
// ---------------------------------------------------------------------------
template <int EPI>
__global__ __launch_bounds__(256) void gemm_bt(
    const ushort* __restrict__ A, const ushort* __restrict__ Bt,
    const float* __restrict__ bias,
    float* __restrict__ Out, ushort* __restrict__ Qb,
    ushort* __restrict__ Kb, ushort* __restrict__ Vtb)
{
    const int m0 = blockIdx.y * 128;
    const int n0 = blockIdx.x * 128;
    const int t  = threadIdx.x;
    const int wave = t >> 6, lane = t & 63;
    const int ln = lane & 15, quad = lane >> 4;
    const int wm = wave >> 1, wn = wave & 1;

    __shared__ ushort As[128 * 64];
    __shared__ ushort Bs[128 * 64];

    f32x4 acc[4][4] = {};

    for (int k0 = 0; k0 < Kdim; k0 += 64) {
        __syncthreads();
        #pragma unroll
        for (int it = 0; it < 4; it++) {
            int c = it * 256 + wave * 64 + lane;
            int row = c >> 3, seg = c & 7;
            int gseg = seg ^ (row & 7);
            gload_lds16(&A [(size_t)(m0 + row) * Kdim + k0 + gseg * 8], &As[c * 8]);
            gload_lds16(&Bt[(size_t)(n0 + row) * Kdim + k0 + gseg * 8], &Bs[c * 8]);
        }
        __syncthreads();

        #pragma unroll
        for (int ks = 0; ks < 2; ks++) {
            bf16x8 af[4], bf[4];
            #pragma unroll
            for (int mm = 0; mm < 4; mm++) {
                int row = wm * 64 + mm * 16 + ln;
                int seg = (ks * 4 + quad) ^ (ln & 7);
                B8 tmp; tmp.u = *(const uint4*)&As[row * 64 + seg * 8];
                af[mm] = tmp.f;
            }
            #pragma unroll
            for (int nn = 0; nn < 4; nn++) {
                int row = wn * 64 + nn * 16 + ln;
                int seg = (ks * 4 + quad) ^ (ln & 7);
                B8 tmp; tmp.u = *(const uint4*)&Bs[row * 64 + seg * 8];
                bf[nn] = tmp.f;
            }
            #pragma unroll
            for (int mm = 0; mm < 4; mm++)
                #pragma unroll
                for (int nn = 0; nn < 4; nn++)
                    acc[mm][nn] = __builtin_amdgcn_mfma_f32_16x16x32_bf16(
                        af[mm], bf[nn], acc[mm][nn], 0, 0, 0);
        }
    }

    if (EPI == 0) {
        #pragma unroll
        for (int nn = 0; nn < 4; nn++) {
            int n = n0 + wn * 64 + nn * 16 + ln;
            float bv = bias[n];
            #pragma unroll
            for (int mm = 0; mm < 4; mm++) {
                int mbase = m0 + wm * 64 + mm * 16 + quad * 4;
                #pragma unroll
                for (int reg = 0; reg < 4; reg++)
                    Out[(size_t)(mbase + reg) * 1024 + n] = acc[mm][nn][reg] + bv;
            }
        }
    } else {
        const int nb = n0 + wn * 64;
        const int which = nb >> 10;            // 0=Q 1=K 2=V
        const int h = (nb & 1023) >> 6;
        const float scale = (which == 0) ? 0.125f * 1.44269504088896f : 1.0f;
        const int b_ = m0 >> 11;               // 128-row tile within one batch
        const int t0 = (m0 & 2047) + wm * 64;

        __syncthreads();   // fragments consumed; reuse As/Bs as transpose pads
        ushort* tile = ((wave & 2) ? Bs : As) + (wave & 1) * 4096;  // 64x64/wave

        if (which == 2) {
            // LDS tile [n=d][m=token] (XOR-swizzled), rows -> [B,H,D,T]
            #pragma unroll
            for (int nn = 0; nn < 4; nn++) {
                float bv = bias[nb + nn * 16 + ln];
                #pragma unroll
                for (int mm = 0; mm < 4; mm++)
                    #pragma unroll
                    for (int reg = 0; reg < 4; reg++) {
                        int m = mm * 16 + quad * 4 + reg;
                        int n = nn * 16 + ln;
                        tile[n * 64 + (m ^ (((n >> 1) & 7) * 8))] =
                            f2bf(acc[mm][nn][reg] + bv);
                    }
            }
            #pragma unroll
            for (int it = 0; it < 8; it++) {
                int idx = it * 64 + lane;
                int row = idx >> 3, seg = idx & 7;   // row = d, seg = token/8
                uint4 v = *(const uint4*)&tile[row * 64 +
                              ((seg * 8) ^ (((row >> 1) & 7) * 8))];
                *(uint4*)&Vtb[((size_t)((b_ * Hn + h) * Dn) + row) * Tn + t0 + seg * 8] = v;
            }
        } else {
            // LDS tile [m=token][n=d] (XOR-swizzled), rows -> [B,H,T,D]
            ushort* dst = (which == 0) ? Qb : Kb;
            #pragma unroll
            for (int nn = 0; nn < 4; nn++) {
                float bv = bias[nb + nn * 16 + ln];
                #pragma unroll
                for (int mm = 0; mm < 4; mm++)
                    #pragma unroll
                    for (int reg = 0; reg < 4; reg++) {
                        int m = mm * 16 + quad * 4 + reg;
                        int n = nn * 16 + ln;
                        tile[m * 64 + (n ^ (((m >> 1) & 7) * 8))] =
                            f2bf((acc[mm][nn][reg] + bv) * scale);
                    }
            }
            #pragma unroll
            for (int it = 0; it < 8; it++) {
                int idx = it * 64 + lane;
                int row = idx >> 3, seg = idx & 7;   // row = token, seg = d/8
                uint4 v = *(const uint4*)&tile[row * 64 +
                              ((seg * 8) ^ (((row >> 1) & 7) * 8))];
                *(uint4*)&dst[((size_t)((b_ * Hn + h) * Tn) + t0 + row) * Dn + seg * 8] = v;
            }
        }
    }
}

// ---------------------------------------------------------------------------
// Flash attention (r18): back to the r1 structure (proven fastest base,
// 130 us): 128-row q-tiles paired (15-y, y) -> 17 chunks/block, grid
// (64,8) = 512 balanced blocks = 2/CU, 32 q per wave (2 ns). The 64-row
// experiments (r13-r17) doubled per-chunk fixed costs per unit output and
// never beat this base. New: per-chunk serial-path cuts:
//  1. Batched P roundtrip: write ALL 4 pass-slices per ns (8 ds_writes),
//     ONE lgkm wait, then stream 8 reads + PV MFMAs (was 4 separate
//     write->wait->read roundtrips, ~200cyc each).
//  2. exp2 BEFORE the rescale branch with m_old (defer-max makes rescale
//     rare): the 32 trans ops are independent of the max-tree+shfl chain
//     and overlap it. m_r init = 0 (S <= ~20 -> exp2(S-m_old) finite);
//     rare rescale multiplies P' by alpha before packing (exact math).
//  3. v_cvt_pk_bf16_f32 packing: 16 single-inst packs vs 32 multi-inst
//     __float2bfloat16 conversions. Layout byte-identical to r1's.
// Softmax row-sum via ones-MFMA; defer-max THR=8 (log2); tree max.
// LDS = Ks 32KB + Ps 34KB = 67.6KB -> 2 blocks/CU.
// ---------------------------------------------------------------------------
__global__ __launch_bounds__(256, 2) void attn_mfma(
    const ushort* __restrict__ Qb, const ushort* __restrict__ Kb,
    const ushort* __restrict__ Vtb, ushort* __restrict__ Ob)
{
    const int bh   = blockIdx.x;       // 0..63 (fastest-varying)
    const int yp   = blockIdx.y;       // 0..7: pair (15-yp, yp)
    const int t    = threadIdx.x;
    const int wave = t >> 6, lane = t & 63;
    const int ln   = lane & 15, quad = lane >> 4;

    __shared__ ushort Ks[2][128 * 64];       // [key][d], xor-swizzled segs
    __shared__ ushort Ps[4][2][4][16 * 34];  // [wave][ns][pass][q(16)*34]

    const ushort* KgB = Kb  + (size_t)bh * Tn * Dn;
    const ushort* VgB = Vtb + (size_t)bh * Dn * Tn;
    const int b_ = bh >> 4, h = bh & 15;

    // all-ones bf16 A-fragment for the l row-sum MFMA
    B8 ones;
    #pragma unroll
    for (int j = 0; j < 8; j++) ones.s[j] = 0x3F80;

    #define STAGE_K(kc, buf)                                                   \
        do {                                                                   \
            _Pragma("unroll")                                                  \
            for (int it = 0; it < 4; it++) {                                   \
                int c = it * 256 + wave * 64 + lane;                           \
                int row = c >> 3, seg = c & 7;                                 \
                int gs = seg ^ (row & 7);                                      \
                gload_lds16(&KgB[(size_t)((kc) * 128 + row) * Dn + gs * 8],    \
                            &Ks[buf][c * 8]);                                  \
            }                                                                  \
        } while (0)

    for (int pass = 0; pass < 2; pass++) {
        const int qt = pass ? yp : 15 - yp;
        if (pass) __syncthreads();     // protect Ks reuse from pass-0 readers

        int cur = 0;
        STAGE_K(0, 0);

        const int q0 = qt * 128;
        const ushort* Qg = Qb + ((size_t)bh * Tn + q0 + wave * 32) * Dn;
        bf16x8 qf[2][2];
        #pragma unroll
        for (int ns = 0; ns < 2; ns++)
            #pragma unroll
            for (int ks = 0; ks < 2; ks++) {
                B8 tmp; tmp.u = *(const uint4*)&Qg[(ns * 16 + ln) * 64 + ks * 32 + quad * 8];
                qf[ns][ks] = tmp.f;
            }

        f32x4 Oacc[4][2] = {};   // O^T [d-subtile][ns], lane ln = q
        f32x4 Lacc[2] = {};      // row-sum accumulator (rows replicated)
        float m_r[2] = {0.f, 0.f};   // init 0: exp2-first scheme needs finite S-m

        for (int kc = 0; kc <= qt; kc++) {
            __syncthreads();   // publishes K(kc); drains prefetch issued last iter

            // V^T fragments: direct global->VGPR, A-layout natural in [B,H,D,T]
            B8 vfr[4][4];      // [d-subtile][32-key step]
            #pragma unroll
            for (int gks = 0; gks < 4; gks++)
                #pragma unroll
                for (int ctd = 0; ctd < 4; ctd++)
                    vfr[ctd][gks].u = *(const uint4*)&VgB[
                        (size_t)(ctd * 16 + ln) * Tn + kc * 128 + gks * 32 + quad * 8];

            if (kc < qt) STAGE_K(kc + 1, cur ^ 1);   // prefetch next chunk

            // S^T = K Q^T: rows = keys (128 = 8 ct), cols = q (32 = 2 ns)
            const ushort* Kc = Ks[cur];
            f32x4 S[8][2] = {};
            #pragma unroll
            for (int ks = 0; ks < 2; ks++)
                #pragma unroll
                for (int ct = 0; ct < 8; ct++) {
                    B8 a; a.u = *(const uint4*)&Kc[(ct * 16 + ln) * 64 +
                                                   (((ks * 4 + quad) ^ (ln & 7)) * 8)];
                    #pragma unroll
                    for (int ns = 0; ns < 2; ns++)
                        S[ct][ns] = __builtin_amdgcn_mfma_f32_16x16x32_bf16(
                            a.f, qf[ns][ks], S[ct][ns], 0, 0, 0);
                }

            if (kc == qt) {   // causal mask on diagonal chunk
                #pragma unroll
                for (int ct = 0; ct < 8; ct++) {
                    int keyl = ct * 16 + quad * 4;
                    #pragma unroll
                    for (int ns = 0; ns < 2; ns++) {
                        int ql = wave * 32 + ns * 16 + ln;
                        #pragma unroll
                        for (int reg = 0; reg < 4; reg++)
                            if (keyl + reg > ql) S[ct][ns][reg] = -1e30f;
                    }
                }
            }

            // per-lane chunk max (tree), reduce over quads
            float pm[2], m_old[2];
            #pragma unroll
            for (int ns = 0; ns < 2; ns++) {
                m_old[ns] = m_r[ns];
                float ctm[8];
                #pragma unroll
                for (int ct = 0; ct < 8; ct++)
                    ctm[ct] = fmaxf(fmaxf(S[ct][ns][0], S[ct][ns][1]),
                                    fmaxf(S[ct][ns][2], S[ct][ns][3]));
                float p = fmaxf(fmaxf(fmaxf(ctm[0], ctm[1]), fmaxf(ctm[2], ctm[3])),
                                fmaxf(fmaxf(ctm[4], ctm[5]), fmaxf(ctm[6], ctm[7])));
                p = fmaxf(p, __shfl_xor(p, 16));
                p = fmaxf(p, __shfl_xor(p, 32));
                pm[ns] = p;
            }

            // exp2 with OLD max — independent of the shuffle chain above, so
            // the scheduler overlaps the 64 trans ops with shuffle latency.
            // Safe: S - m_old <= ~20 << 128 (m_old >= 0), masked -> exp2 -> 0.
            #pragma unroll
            for (int ns = 0; ns < 2; ns++)
                #pragma unroll
                for (int ct = 0; ct < 8; ct++)
                    #pragma unroll
                    for (int reg = 0; reg < 4; reg++)
                        S[ct][ns][reg] = exp2f(S[ct][ns][reg] - m_old[ns]);

            // defer-max: rescale only when some lane's max grew by > 8 (log2)
            bool need = (pm[0] > m_old[0] + 8.0f) | (pm[1] > m_old[1] + 8.0f);
            if (__any(need)) {
                #pragma unroll
                for (int ns = 0; ns < 2; ns++) {
                    float mn = fmaxf(m_old[ns], pm[ns]);
                    float alpha = exp2f(m_old[ns] - mn);
                    m_r[ns] = mn;
                    #pragma unroll
                    for (int ct = 0; ct < 8; ct++)
                        #pragma unroll
                        for (int reg = 0; reg < 4; reg++)
                            S[ct][ns][reg] *= alpha;
                    #pragma unroll
                    for (int ctd = 0; ctd < 4; ctd++)
                        Oacc[ctd][ns] *= alpha;
                    Lacc[ns] *= alpha;
                }
            }

            // pack ALL P (v_cvt_pk_bf16_f32) and write all 8 pass-slices,
            // then ONE wait and stream the 8 reads + PV MFMAs.
            #pragma unroll
            for (int ns = 0; ns < 2; ns++)
                #pragma unroll
                for (int ct = 0; ct < 8; ct++) {
                    float s0 = S[ct][ns][0], s1 = S[ct][ns][1];
                    float s2 = S[ct][ns][2], s3 = S[ct][ns][3];
                    uint w0, w1;
                    asm("v_cvt_pk_bf16_f32 %0, %1, %2" : "=v"(w0) : "v"(s0), "v"(s1));
                    asm("v_cvt_pk_bf16_f32 %0, %1, %2" : "=v"(w1) : "v"(s2), "v"(s3));
                    uint2 o; o.x = w0; o.y = w1;
                    *(uint2*)&Ps[wave][ns][ct >> 1]
                        [ln * 34 + (ct & 1) * 16 + quad * 4] = o;
                }

            #pragma unroll
            for (int p = 0; p < 4; p++)
                #pragma unroll
                for (int ns = 0; ns < 2; ns++) {
                    B8 pfr; pfr.u = *(const uint4*)&Ps[wave][ns][p]
                        [ln * 34 + quad * 8];
                    #pragma unroll
                    for (int ctd = 0; ctd < 4; ctd++)
                        Oacc[ctd][ns] = __builtin_amdgcn_mfma_f32_16x16x32_bf16(
                            vfr[ctd][p].f, pfr.f, Oacc[ctd][ns], 0, 0, 0);
                    Lacc[ns] = __builtin_amdgcn_mfma_f32_16x16x32_bf16(
                        ones.f, pfr.f, Lacc[ns], 0, 0, 0);
                }
            cur ^= 1;
        }

        // epilogue: bf16 attn_out [B*T][C]; lane ln = token, regs = d
        #pragma unroll
        for (int ns = 0; ns < 2; ns++) {
            float inv = 1.0f / Lacc[ns][0];
            int token = q0 + wave * 32 + ns * 16 + ln;
            ushort* dst = Ob + ((size_t)(b_ * Tn + token)) * Cn + h * 64;
            #pragma unroll
            for (int ctd = 0; ctd < 4; ctd++) {
                ushort4 o;
                #pragma unroll
                for (int reg = 0; reg < 4; reg++)
                    ((ushort*)&o)[reg] = f2bf(Oacc[ctd][ns][reg] * inv);
                *(ushort4*)&dst[ctd * 16 + quad * 4] = o;
            }
        }
    }
    #undef STAGE_K
}

// ---------------------------------------------------------------------------
extern "C" void kernel_launch(void* const* d_in, const int* in_sizes, int n_in,
                              void* d_out, int out_size, void* d_ws, size_t ws_size,
                              hipStream_t stream) {
    const float* X     = (const float*)d_in[0];
    const float* qkv_w = (const float*)d_in[1];
    const float* qkv_b = (const float*)d_in[2];
    const float* o_w   = (const float*)d_in[3];
    const float* o_b   = (const float*)d_in[4];
    float* out = (float*)d_out;

    const size_t BTC = (size_t)Bn * Tn * Cn;     // 8388608
    ushort* Xb  = (ushort*)d_ws;                 // bf16 [8192,1024]
    ushort* Wqt = Xb  + BTC;                     // bf16 [3072,1024]
    ushort* Wot = Wqt + 3 * Cn * Cn;             // bf16 [1024,1024]
    ushort* Qb  = Wot + Cn * Cn;                 // bf16 [B,H,T,D]
    ushort* Kb  = Qb  + BTC;
    ushort* Vtb = Kb  + BTC;                     // bf16 [B,H,D,T]
    ushort* Ao  = Vtb + BTC;                     // bf16 [B*T,C]

    // fused prep: y=0 cast (4096 blocks), y=1 qkv_w transpose (96*32=3072),
    // y=2 o_w transpose (32*32=1024). grid.x = max section size.
    prep_fused<<<dim3(4096, 3), 256, 0, stream>>>(X, qkv_w, o_w, Xb, Wqt, Wot);

    gemm_bt<1><<<dim3(3 * Cn / 128, 8192 / 128), 256, 0, stream>>>(
        Xb, Wqt, qkv_b, nullptr, Qb, Kb, Vtb);
    attn_mfma<<<dim3(Bn * Hn, 8), 256, 0, stream>>>(Qb, Kb, Vtb, Ao);
    gemm_bt<0><<<dim3(Cn / 128, 8192 / 128), 256, 0, stream>>>(
        Ao, Wot, o_b, out, nullptr, nullptr, nullptr);
}